// Round 2
// baseline (3059.831 us; speedup 1.0000x reference)
//
#include <hip/hip_runtime.h>
#include <hip/hip_bf16.h>

// PatchEmbed: B=8, N=16384, M=2048, K=32, EMB=256. Dtype of float tensors is
// runtime-sniffed (bf16 vs f32) because the harness's conversion policy is
// ambiguous; idx is int32 either way. One block per (b, m) center; 256 thr.
//
// Stage 0: gather 32 neighbors, center-subtract -> loc[32][4] f32 in LDS
// Stage 1: h1 = relu(loc @ W1^T + b1)  -> LDS f32 [32][64]  (stride 68)
// Stage 2: h2 = relu(h1 @ W2^T + b2)   -> LDS f32 [32][128] (stride 132)
// Stage 3: per-thread output channel o: W3 row packed bf16 in 16 uint4 regs;
//          h2 via wave-broadcast float4 LDS loads; max over k.

#define BF_LO(u) __uint_as_float(((unsigned)(u)) << 16)
#define BF_HI(u) __uint_as_float(((unsigned)(u)) & 0xffff0000u)

constexpr int Bn   = 8;
constexpr int Nn   = 16384;
constexpr int Mn   = 2048;
constexpr int Kn   = 32;
constexpr int C1   = 64;
constexpr int C2   = 128;
constexpr int EMB  = 256;
constexpr int H1S  = 68;   // h1 row stride (pad)
constexpr int H2S  = 132;  // h2 row stride (pad)
constexpr int W2S  = 68;   // w2f row stride (pad)

__device__ __forceinline__ float ldf(const void* p, size_t i, bool f32) {
    return f32 ? ((const float*)p)[i] : BF_LO(((const ushort*)p)[i]);
}

__device__ __forceinline__ unsigned pack2(float lo, float hi) {
    __hip_bfloat16 l = __float2bfloat16(lo);
    __hip_bfloat16 h = __float2bfloat16(hi);
    return (unsigned)*(unsigned short*)&l |
           ((unsigned)*(unsigned short*)&h << 16);
}

__global__ __launch_bounds__(256, 2) void patch_embed_kernel(
    const void* __restrict__ xyz,      // (B,N,3)
    const void* __restrict__ centers,  // (B,M,3)
    const int*  __restrict__ idx,      // (B,M,K) i32
    const void* __restrict__ W1,       // (64,3)
    const void* __restrict__ b1,       // (64,)
    const void* __restrict__ W2,       // (128,64)
    const void* __restrict__ b2,       // (128,)
    const void* __restrict__ W3,       // (256,128)
    const void* __restrict__ b3,       // (256,)
    void*       __restrict__ out)      // (B,M,256)
{
    __shared__ float loc[Kn][4];
    __shared__ float h1[Kn * H1S];
    __shared__ float h2[Kn * H2S];
    __shared__ float w2f[C2 * W2S];
    __shared__ float w1f[C1 * 3];
    __shared__ float b1f[C1];
    __shared__ float b2f[C2];
    __shared__ float b3f[EMB];

    const int tid = threadIdx.x;
    const int bm  = blockIdx.x;          // b*2048 + m
    const int b   = bm >> 11;
    const int m   = bm & (Mn - 1);

    // ---- dtype sniff: bf16 weights have exponent <= ~0x81; f32 data read as
    // ushorts has random exponent fields in its mantissa halves. Uniform
    // across all threads (same addresses), recomputed every launch. ----
    bool isf32;
    {
        const unsigned short* W1u = (const unsigned short*)W1;
        int big = 0;
        #pragma unroll
        for (int i = 0; i < 64; ++i) {
            unsigned e = (W1u[i] >> 7) & 0xFFu;
            big += (e >= 0x85u) ? 1 : 0;
        }
        isf32 = (big > 4);
    }

    // ---- stage weights into LDS as f32 ----
    if (isf32) {
        const float4* W2v = (const float4*)W2;   // 2048 float4 (4 f32 each)
        #pragma unroll
        for (int i = 0; i < 8; ++i) {
            int e   = tid + i * 256;             // chunk id, 16 per 64-wide row
            float4 w = W2v[e];
            int row = e >> 4;
            int col = (e & 15) * 4;
            float* dst = &w2f[row * W2S + col];
            dst[0] = w.x; dst[1] = w.y; dst[2] = w.z; dst[3] = w.w;
        }
    } else {
        const uint4* W2v = (const uint4*)W2;     // 1024 uint4 (8 bf16 each)
        #pragma unroll
        for (int i = 0; i < 4; ++i) {
            int e   = tid + i * 256;             // chunk id, 8 per 64-wide row
            uint4 w = W2v[e];
            int row = e >> 3;
            int col = (e & 7) * 8;
            float* dst = &w2f[row * W2S + col];
            dst[0] = BF_LO(w.x); dst[1] = BF_HI(w.x);
            dst[2] = BF_LO(w.y); dst[3] = BF_HI(w.y);
            dst[4] = BF_LO(w.z); dst[5] = BF_HI(w.z);
            dst[6] = BF_LO(w.w); dst[7] = BF_HI(w.w);
        }
    }
    if (tid < C1 * 3) w1f[tid] = ldf(W1, tid, isf32);
    if (tid < C1)     b1f[tid] = ldf(b1, tid, isf32);
    if (tid < C2)     b2f[tid] = ldf(b2, tid, isf32);
    b3f[tid] = ldf(b3, tid, isf32);

    // ---- gather + center subtract ----
    if (tid < Kn) {
        int id = idx[(size_t)bm * Kn + tid];
        size_t pb = ((size_t)b * Nn + id) * 3;
        size_t cb = ((size_t)b * Mn + m) * 3;
        loc[tid][0] = ldf(xyz, pb + 0, isf32) - ldf(centers, cb + 0, isf32);
        loc[tid][1] = ldf(xyz, pb + 1, isf32) - ldf(centers, cb + 1, isf32);
        loc[tid][2] = ldf(xyz, pb + 2, isf32) - ldf(centers, cb + 2, isf32);
    }
    __syncthreads();

    const int k     = tid >> 3;   // 8 threads per k-row
    const int lane8 = tid & 7;

    // ---- stage 1: h1 = relu(loc @ W1^T + b1), 32x64 ----
    {
        float x0 = loc[k][0], x1 = loc[k][1], x2 = loc[k][2];
        #pragma unroll
        for (int j = 0; j < 8; ++j) {
            int o = lane8 + 8 * j;
            float a = b1f[o] + x0 * w1f[o * 3 + 0]
                             + x1 * w1f[o * 3 + 1]
                             + x2 * w1f[o * 3 + 2];
            h1[k * H1S + o] = fmaxf(a, 0.f);
        }
    }
    __syncthreads();

    // ---- stage 2: h2 = relu(h1 @ W2^T + b2), 32x128 ----
    {
        float acc[16];
        #pragma unroll
        for (int j = 0; j < 16; ++j) acc[j] = b2f[lane8 + 8 * j];
        const float* h1r = &h1[k * H1S];
        #pragma unroll 4
        for (int c4 = 0; c4 < 16; ++c4) {
            float4 hv = *(const float4*)&h1r[c4 * 4];
            #pragma unroll
            for (int j = 0; j < 16; ++j) {
                int o2 = lane8 + 8 * j;
                float4 wv = *(const float4*)&w2f[o2 * W2S + c4 * 4];
                acc[j] += hv.x * wv.x + hv.y * wv.y + hv.z * wv.z + hv.w * wv.w;
            }
        }
        #pragma unroll
        for (int j = 0; j < 16; ++j)
            h2[k * H2S + lane8 + 8 * j] = fmaxf(acc[j], 0.f);
    }
    __syncthreads();

    // ---- stage 3: h3 = h2 @ W3^T + b3, max over k, 256 outputs ----
    {
        const int o = tid;
        uint4 w3p[16];   // W3 row packed as 128 bf16 (both dtype paths)
        if (isf32) {
            const float4* W3v = (const float4*)W3 + (size_t)o * 32;
            #pragma unroll
            for (int i = 0; i < 16; ++i) {
                float4 a = W3v[2 * i];
                float4 c = W3v[2 * i + 1];
                w3p[i] = make_uint4(pack2(a.x, a.y), pack2(a.z, a.w),
                                    pack2(c.x, c.y), pack2(c.z, c.w));
            }
        } else {
            const uint4* W3v = (const uint4*)W3 + (size_t)o * 16;
            #pragma unroll
            for (int i = 0; i < 16; ++i) w3p[i] = W3v[i];
        }

        const float bias = b3f[o];
        float mx = -3.0e38f;
        #pragma unroll 1
        for (int kk = 0; kk < Kn; ++kk) {
            const float4* hr = (const float4*)&h2[kk * H2S];
            float acc = bias;
            #pragma unroll
            for (int i = 0; i < 16; ++i) {
                uint4 w  = w3p[i];
                float4 a = hr[2 * i];
                float4 c = hr[2 * i + 1];
                acc += a.x * BF_LO(w.x) + a.y * BF_HI(w.x)
                     + a.z * BF_LO(w.y) + a.w * BF_HI(w.y)
                     + c.x * BF_LO(w.z) + c.y * BF_HI(w.z)
                     + c.z * BF_LO(w.w) + c.w * BF_HI(w.w);
            }
            mx = fmaxf(mx, acc);
        }
        if (isf32) {
            ((float*)out)[(size_t)bm * EMB + o] = mx;
        } else {
            __hip_bfloat16 r = __float2bfloat16(mx);
            ((unsigned short*)out)[(size_t)bm * EMB + o] = *(unsigned short*)&r;
        }
    }
}

extern "C" void kernel_launch(void* const* d_in, const int* in_sizes, int n_in,
                              void* d_out, int out_size, void* d_ws, size_t ws_size,
                              hipStream_t stream) {
    const void* xyz     = d_in[0];
    const void* centers = d_in[1];
    const int*  idx     = (const int*)d_in[2];
    const void* W1      = d_in[3];
    const void* b1      = d_in[4];
    const void* W2      = d_in[5];
    const void* b2      = d_in[6];
    const void* W3      = d_in[7];
    const void* b3      = d_in[8];

    dim3 grid(Bn * Mn);   // 16384 blocks, one per (b, m)
    dim3 block(256);
    patch_embed_kernel<<<grid, block, 0, stream>>>(
        xyz, centers, idx, W1, b1, W2, b2, W3, b3, d_out);
}

// Round 3
// 195.434 us; speedup vs baseline: 15.6566x; 15.6566x over previous
//
#include <hip/hip_runtime.h>
#include <hip/hip_bf16.h>

// PatchEmbed MFMA rewrite. Data dtype = f32 (proven: round-1 pure-bf16 -> inf,
// round-2 sniffer f32 path -> passed). B=8,N=16384,M=2048,K=32,EMB=256.
// G=4 centers/block (128 rows), 4096 blocks, 256 threads (4 waves).
//   stage1 (3->64): f32 VALU, h1 -> LDS bf16 frag-major [T][oct][row16][8]
//   stage2 (64->128): mfma 16x16x32 bf16, wave owns 32 cols; C-frags ->
//                     relu+bias -> bf16 scatter into h2 LDS (stage-3 A layout)
//   stage3 (128->256): mfma, wave owns 64 cols; max over K in C-regs +
//                     shfl_xor(16,32); +b3 after max (b3 const per channel).
// W2/W3 B-fragments: f32 global -> bf16 regs, loaded once per block.

typedef __attribute__((ext_vector_type(8))) short bf16x8;
typedef __attribute__((ext_vector_type(4))) float f32x4v;

constexpr int Bn = 8, Nn = 16384, Mn = 2048, Kn = 32, EMB = 256;
constexpr int G = 4;              // centers per block
constexpr int ROWS = G * Kn;      // 128 rows per block

__device__ __forceinline__ unsigned short bfr(float x) {   // f32 -> bf16 RTN
    unsigned u = __float_as_uint(x);
    u += 0x7fffu + ((u >> 16) & 1u);
    return (unsigned short)(u >> 16);
}

__device__ __forceinline__ bf16x8 pack8(const float* v) {
    bf16x8 r;
    #pragma unroll
    for (int i = 0; i < 8; ++i) r[i] = (short)bfr(v[i]);
    return r;
}

__global__ __launch_bounds__(256, 2) void pe_mfma(
    const float* __restrict__ xyz,      // (B,N,3)
    const float* __restrict__ centers,  // (B,M,3)
    const int*   __restrict__ idx,      // (B,M,K)
    const float* __restrict__ W1,       // (64,3)
    const float* __restrict__ b1,       // (64,)
    const float* __restrict__ W2,       // (128,64)
    const float* __restrict__ b2,       // (128,)
    const float* __restrict__ W3,       // (256,128)
    const float* __restrict__ b3,       // (256,)
    float*       __restrict__ out)      // (B,M,256)
{
    __shared__ uint4  h1v[ROWS * 64 * 2 / 16];    // 1024 uint4 = 16 KB
    __shared__ uint4  h2v[ROWS * 128 * 2 / 16];   // 2048 uint4 = 32 KB
    __shared__ float4 w1v[48];                    // 192 f32
    __shared__ float  b1f[64];

    const int tid = threadIdx.x;
    const int w   = tid >> 6;          // wave 0..3
    const int l   = tid & 63;
    const int q   = l >> 4;            // quad 0..3
    const int n   = l & 15;            // frag row/col index
    const int bm0 = blockIdx.x * G;    // first global center of this block

    // ---- B-fragments (held in regs for the whole block) ----
    // B[k][n] layout: lane(q,n) holds 8 consecutive k for its column n.
    bf16x8 B2f[2][2];                  // stage2: wave cols w*32 + ct*16 + n
    bf16x8 B3f[4][4];                  // stage3: wave cols w*64 + ct*16 + n
    float  b2v[2], b3v[4];
    #pragma unroll
    for (int ct = 0; ct < 2; ++ct) {
        int ch = w * 32 + ct * 16 + n;
        b2v[ct] = b2[ch];
        #pragma unroll
        for (int kt = 0; kt < 2; ++kt) {
            const float* p = W2 + ch * 64 + kt * 32 + q * 8;
            float t[8];
            *(float4*)&t[0] = *(const float4*)p;
            *(float4*)&t[4] = *(const float4*)(p + 4);
            B2f[ct][kt] = pack8(t);
        }
    }
    #pragma unroll
    for (int ct = 0; ct < 4; ++ct) {
        int ch = w * 64 + ct * 16 + n;
        b3v[ct] = b3[ch];
        #pragma unroll
        for (int kt = 0; kt < 4; ++kt) {
            const float* p = W3 + ch * 128 + kt * 32 + q * 8;
            float t[8];
            *(float4*)&t[0] = *(const float4*)p;
            *(float4*)&t[4] = *(const float4*)(p + 4);
            B3f[ct][kt] = pack8(t);
        }
    }

    if (tid < 48) w1v[tid] = ((const float4*)W1)[tid];
    if (tid < 64) b1f[tid] = b1[tid];

    // ---- gather + center-subtract (threads 0..127, one row each) ----
    float lx = 0.f, ly = 0.f, lz = 0.f;
    if (tid < ROWS) {
        int bm = bm0 + (tid >> 5);            // global center index = b*2048+m
        int b  = bm >> 11;
        int id = idx[(size_t)bm * Kn + (tid & 31)];
        const float* p = xyz + ((size_t)b * Nn + id) * 3;
        const float* c = centers + (size_t)bm * 3;
        lx = p[0] - c[0]; ly = p[1] - c[1]; lz = p[2] - c[2];
    }
    __syncthreads();   // w1v/b1f ready

    // ---- stage 1: h1 = relu(loc @ W1^T + b1), write bf16 frags ----
    if (tid < ROWS) {
        float h[64];
        #pragma unroll
        for (int o4 = 0; o4 < 16; ++o4) {
            float4 wa = w1v[3 * o4], wb = w1v[3 * o4 + 1], wc = w1v[3 * o4 + 2];
            h[4*o4+0] = fmaxf(b1f[4*o4+0] + lx*wa.x + ly*wa.y + lz*wa.z, 0.f);
            h[4*o4+1] = fmaxf(b1f[4*o4+1] + lx*wa.w + ly*wb.x + lz*wb.y, 0.f);
            h[4*o4+2] = fmaxf(b1f[4*o4+2] + lx*wb.z + ly*wb.w + lz*wc.x, 0.f);
            h[4*o4+3] = fmaxf(b1f[4*o4+3] + lx*wc.y + ly*wc.z + lz*wc.w, 0.f);
        }
        int T = tid >> 4, r = tid & 15;
        #pragma unroll
        for (int j = 0; j < 8; ++j) {          // 8 k-octets of 64 channels
            bf16x8 v = pack8(&h[8 * j]);
            h1v[T * 128 + j * 16 + r] = *(uint4*)&v;
        }
    }
    __syncthreads();

    // ---- stage 2: h2 = relu(h1 @ W2^T + b2), MFMA, wave owns 32 cols ----
    {
        ushort* h2s = (ushort*)h2v;
        for (int rt = 0; rt < 8; ++rt) {
            uint4 a0u = h1v[rt * 128 + q * 16 + n];          // kt=0, oct=q
            uint4 a1u = h1v[rt * 128 + (4 + q) * 16 + n];    // kt=1, oct=4+q
            bf16x8 A0 = *(bf16x8*)&a0u, A1 = *(bf16x8*)&a1u;
            f32x4v C[2];
            #pragma unroll
            for (int ct = 0; ct < 2; ++ct) {
                f32x4v c0 = {0.f, 0.f, 0.f, 0.f};
                c0 = __builtin_amdgcn_mfma_f32_16x16x32_bf16(A0, B2f[ct][0], c0, 0, 0, 0);
                c0 = __builtin_amdgcn_mfma_f32_16x16x32_bf16(A1, B2f[ct][1], c0, 0, 0, 0);
                C[ct] = c0;
            }
            #pragma unroll
            for (int ct = 0; ct < 2; ++ct) {
                int ch = w * 32 + ct * 16 + n;               // out channel
                #pragma unroll
                for (int reg = 0; reg < 4; ++reg) {
                    float v = fmaxf(C[ct][reg] + b2v[ct], 0.f);
                    int rowl = q * 4 + reg;                  // row within tile
                    h2s[rt * 2048 + (ch >> 3) * 128 + rowl * 8 + (ch & 7)] = bfr(v);
                }
            }
        }
    }
    __syncthreads();

    // ---- stage 3: h3 = h2 @ W3^T, max over K, +b3; wave owns 64 cols ----
    {
        float cmax[4];
        for (int rt = 0; rt < 8; ++rt) {       // 8 row-tiles = 4 centers
            bf16x8 A[4];
            #pragma unroll
            for (int kt = 0; kt < 4; ++kt) {
                uint4 au = h2v[rt * 256 + (kt * 4 + q) * 16 + n];
                A[kt] = *(bf16x8*)&au;
            }
            #pragma unroll
            for (int ct = 0; ct < 4; ++ct) {
                f32x4v C = {0.f, 0.f, 0.f, 0.f};
                #pragma unroll
                for (int kt = 0; kt < 4; ++kt)
                    C = __builtin_amdgcn_mfma_f32_16x16x32_bf16(A[kt], B3f[ct][kt], C, 0, 0, 0);
                float v = fmaxf(fmaxf(C[0], C[1]), fmaxf(C[2], C[3]));
                v = fmaxf(v, __shfl_xor(v, 16));
                v = fmaxf(v, __shfl_xor(v, 32));   // max over 16 rows of tile
                if ((rt & 1) == 0) {
                    cmax[ct] = v;
                } else if (q == 0) {               // lanes 0..15 store
                    float r = fmaxf(cmax[ct], v) + b3v[ct];
                    out[(size_t)(bm0 + (rt >> 1)) * EMB + w * 64 + ct * 16 + n] = r;
                }
            }
        }
    }
}

extern "C" void kernel_launch(void* const* d_in, const int* in_sizes, int n_in,
                              void* d_out, int out_size, void* d_ws, size_t ws_size,
                              hipStream_t stream) {
    const float* xyz     = (const float*)d_in[0];
    const float* centers = (const float*)d_in[1];
    const int*   idx     = (const int*)  d_in[2];
    const float* W1      = (const float*)d_in[3];
    const float* b1      = (const float*)d_in[4];
    const float* W2      = (const float*)d_in[5];
    const float* b2      = (const float*)d_in[6];
    const float* W3      = (const float*)d_in[7];
    const float* b3      = (const float*)d_in[8];
    float*       out     = (float*)d_out;

    dim3 grid((Bn * Mn) / G);   // 4096 blocks
    dim3 block(256);
    pe_mfma<<<grid, block, 0, stream>>>(
        xyz, centers, idx, W1, b1, W2, b2, W3, b3, out);
}

// Round 4
// 127.416 us; speedup vs baseline: 24.0145x; 1.5338x over previous
//
#include <hip/hip_runtime.h>
#include <hip/hip_bf16.h>

// PatchEmbed MFMA v2. Data dtype f32 (proven R1/R2). B=8,N=16384,M=2048,K=32.
// Two launches on `stream`:
//   pe_pack: W2/W3 f32 -> bf16 MFMA B-fragments in d_ws (80 KB), per-lane order.
//   pe_mfma: G=2 centers/block (64 rows), 8192 blocks, 256 thr, LDS 26 KB ->
//            4 blocks/CU resident (vs 2 at G=4) to hide barrier/LDS latency.
//   stage1 (3->64): f32 VALU, all 256 threads (thread = row x 16-ch group)
//   stage2 (64->128): mfma 16x16x32 bf16, wave owns 32 cols -> bf16 scatter
//   stage3 (128->256): mfma, wave owns 64 cols; max over K in C-regs +
//                      shfl_xor(16,32); +b3 after max.

typedef __attribute__((ext_vector_type(8))) short bf16x8;
typedef __attribute__((ext_vector_type(4))) float f32x4v;

constexpr int Bn = 8, Nn = 16384, Mn = 2048, Kn = 32, EMB = 256;
constexpr int G = 2;              // centers per block
constexpr int ROWS = G * Kn;      // 64 rows per block

__device__ __forceinline__ unsigned short bfr(float x) {   // f32 -> bf16 RTN
    unsigned u = __float_as_uint(x);
    u += 0x7fffu + ((u >> 16) & 1u);
    return (unsigned short)(u >> 16);
}

__device__ __forceinline__ bf16x8 pack8(const float* v) {
    bf16x8 r;
    #pragma unroll
    for (int i = 0; i < 8; ++i) r[i] = (short)bfr(v[i]);
    return r;
}

// ---- kernel A: pack W2 (1024 frags) + W3 (4096 frags) into ws ----
// ws2[((w*2+ct)*2+kt)*64 + l], ws3 at +1024: [((w*4+ct)*4+kt)*64 + l]
__global__ __launch_bounds__(256) void pe_pack(
    const float* __restrict__ W2, const float* __restrict__ W3,
    uint4* __restrict__ ws)
{
    int gid = blockIdx.x * 256 + threadIdx.x;
    if (gid < 1024) {
        int e = gid, l = e & 63;
        int kt = (e >> 6) & 1, ct = (e >> 7) & 1, w = e >> 8;
        int q = l >> 4, n = l & 15;
        int ch = w * 32 + ct * 16 + n;
        const float* p = W2 + ch * 64 + kt * 32 + q * 8;
        float t[8];
        *(float4*)&t[0] = *(const float4*)p;
        *(float4*)&t[4] = *(const float4*)(p + 4);
        bf16x8 v = pack8(t);
        ws[e] = *(uint4*)&v;
    } else if (gid < 5120) {
        int e = gid - 1024, l = e & 63;
        int kt = (e >> 6) & 3, ct = (e >> 8) & 3, w = e >> 10;
        int q = l >> 4, n = l & 15;
        int ch = w * 64 + ct * 16 + n;
        const float* p = W3 + ch * 128 + kt * 32 + q * 8;
        float t[8];
        *(float4*)&t[0] = *(const float4*)p;
        *(float4*)&t[4] = *(const float4*)(p + 4);
        bf16x8 v = pack8(t);
        ws[1024 + e] = *(uint4*)&v;
    }
}

__global__ __launch_bounds__(256, 4) void pe_mfma(
    const float* __restrict__ xyz,      // (B,N,3)
    const float* __restrict__ centers,  // (B,M,3)
    const int*   __restrict__ idx,      // (B,M,K)
    const float* __restrict__ W1,       // (64,3)
    const float* __restrict__ b1,       // (64,)
    const float* __restrict__ b2,       // (128,)
    const float* __restrict__ b3,       // (256,)
    const uint4* __restrict__ wsf,      // packed W2/W3 fragments
    float*       __restrict__ out)      // (B,M,256)
{
    __shared__ uint4  h1v[ROWS * 64 * 2 / 16];    // 512 uint4  = 8 KB
    __shared__ uint4  h2v[ROWS * 128 * 2 / 16];   // 1024 uint4 = 16 KB
    __shared__ float4 w1v[48];
    __shared__ float  b1f[64];

    const int tid = threadIdx.x;
    const int w   = tid >> 6;          // wave 0..3
    const int l   = tid & 63;
    const int q   = l >> 4;            // quad 0..3
    const int n   = l & 15;            // frag row/col index
    const int bm0 = blockIdx.x * G;

    // ---- B-fragments from ws (coalesced uint4, no repack) ----
    bf16x8 B2f[2][2];  float b2v[2];
    #pragma unroll
    for (int ct = 0; ct < 2; ++ct) {
        b2v[ct] = b2[w * 32 + ct * 16 + n];
        #pragma unroll
        for (int kt = 0; kt < 2; ++kt) {
            uint4 u = wsf[((w * 2 + ct) * 2 + kt) * 64 + l];
            B2f[ct][kt] = *(bf16x8*)&u;
        }
    }
    bf16x8 B3f[4][4];  float b3v[4];
    #pragma unroll
    for (int ct = 0; ct < 4; ++ct) {
        b3v[ct] = b3[w * 64 + ct * 16 + n];
        #pragma unroll
        for (int kt = 0; kt < 4; ++kt) {
            uint4 u = wsf[1024 + ((w * 4 + ct) * 4 + kt) * 64 + l];
            B3f[ct][kt] = *(bf16x8*)&u;
        }
    }

    if (tid < 48) w1v[tid] = ((const float4*)W1)[tid];
    if (tid < 64) b1f[tid] = b1[tid];

    // ---- gather + center-subtract (4 threads per row, redundant) ----
    const int r64 = tid & 63;                 // row 0..63
    {
        int bm = bm0 + (r64 >> 5);
        int bb = bm >> 11;
        int id = idx[(size_t)bm * Kn + (r64 & 31)];
        const float* p = xyz + ((size_t)bb * Nn + id) * 3;
        const float* c = centers + (size_t)bm * 3;
        float lx = p[0] - c[0], ly = p[1] - c[1], lz = p[2] - c[2];
        __syncthreads();   // w1v/b1f ready

        // ---- stage 1: thread computes 16 channels of its row ----
        float h[16];
        const int o4b = (tid >> 6) * 4;       // first ch/4 group
        #pragma unroll
        for (int i = 0; i < 4; ++i) {
            int o4 = o4b + i;
            float4 wa = w1v[3 * o4], wb = w1v[3 * o4 + 1], wc = w1v[3 * o4 + 2];
            h[4*i+0] = fmaxf(b1f[4*o4+0] + lx*wa.x + ly*wa.y + lz*wa.z, 0.f);
            h[4*i+1] = fmaxf(b1f[4*o4+1] + lx*wa.w + ly*wb.x + lz*wb.y, 0.f);
            h[4*i+2] = fmaxf(b1f[4*o4+2] + lx*wb.z + ly*wb.w + lz*wc.x, 0.f);
            h[4*i+3] = fmaxf(b1f[4*o4+3] + lx*wc.y + ly*wc.z + lz*wc.w, 0.f);
        }
        const int T = r64 >> 4, r = r64 & 15, j0 = (tid >> 6) * 2;
        #pragma unroll
        for (int jj = 0; jj < 2; ++jj) {
            bf16x8 v = pack8(&h[8 * jj]);
            h1v[T * 128 + (j0 + jj) * 16 + r] = *(uint4*)&v;
        }
    }
    __syncthreads();

    // ---- stage 2: h2 = relu(h1 @ W2^T + b2), wave owns 32 cols ----
    {
        ushort* h2s = (ushort*)h2v;
        for (int rt = 0; rt < G * 2; ++rt) {
            uint4 a0u = h1v[rt * 128 + q * 16 + n];
            uint4 a1u = h1v[rt * 128 + (4 + q) * 16 + n];
            bf16x8 A0 = *(bf16x8*)&a0u, A1 = *(bf16x8*)&a1u;
            #pragma unroll
            for (int ct = 0; ct < 2; ++ct) {
                f32x4v c0 = {0.f, 0.f, 0.f, 0.f};
                c0 = __builtin_amdgcn_mfma_f32_16x16x32_bf16(A0, B2f[ct][0], c0, 0, 0, 0);
                c0 = __builtin_amdgcn_mfma_f32_16x16x32_bf16(A1, B2f[ct][1], c0, 0, 0, 0);
                int ch = w * 32 + ct * 16 + n;
                #pragma unroll
                for (int reg = 0; reg < 4; ++reg) {
                    float v = fmaxf(c0[reg] + b2v[ct], 0.f);
                    int rowl = q * 4 + reg;
                    h2s[rt * 2048 + (ch >> 3) * 128 + rowl * 8 + (ch & 7)] = bfr(v);
                }
            }
        }
    }
    __syncthreads();

    // ---- stage 3: h3 = h2 @ W3^T, max over K, +b3; wave owns 64 cols ----
    {
        float cmax[4];
        for (int rt = 0; rt < G * 2; ++rt) {
            bf16x8 A[4];
            #pragma unroll
            for (int kt = 0; kt < 4; ++kt) {
                uint4 au = h2v[rt * 256 + (kt * 4 + q) * 16 + n];
                A[kt] = *(bf16x8*)&au;
            }
            #pragma unroll
            for (int ct = 0; ct < 4; ++ct) {
                f32x4v C = {0.f, 0.f, 0.f, 0.f};
                #pragma unroll
                for (int kt = 0; kt < 4; ++kt)
                    C = __builtin_amdgcn_mfma_f32_16x16x32_bf16(A[kt], B3f[ct][kt], C, 0, 0, 0);
                float v = fmaxf(fmaxf(C[0], C[1]), fmaxf(C[2], C[3]));
                v = fmaxf(v, __shfl_xor(v, 16));
                v = fmaxf(v, __shfl_xor(v, 32));
                if ((rt & 1) == 0) {
                    cmax[ct] = v;
                } else if (q == 0) {
                    float r = fmaxf(cmax[ct], v) + b3v[ct];
                    out[(size_t)(bm0 + (rt >> 1)) * EMB + w * 64 + ct * 16 + n] = r;
                }
            }
        }
    }
}

extern "C" void kernel_launch(void* const* d_in, const int* in_sizes, int n_in,
                              void* d_out, int out_size, void* d_ws, size_t ws_size,
                              hipStream_t stream) {
    const float* xyz     = (const float*)d_in[0];
    const float* centers = (const float*)d_in[1];
    const int*   idx     = (const int*)  d_in[2];
    const float* W1      = (const float*)d_in[3];
    const float* b1      = (const float*)d_in[4];
    const float* W2      = (const float*)d_in[5];
    const float* b2      = (const float*)d_in[6];
    const float* W3      = (const float*)d_in[7];
    const float* b3      = (const float*)d_in[8];
    float*       out     = (float*)d_out;
    uint4*       ws      = (uint4*)d_ws;    // needs 5120*16 = 80 KB

    pe_pack<<<20, 256, 0, stream>>>(W2, W3, ws);
    pe_mfma<<<(Bn * Mn) / G, 256, 0, stream>>>(
        xyz, centers, idx, W1, b1, b2, b3, ws, out);
}